// Round 2
// baseline (173.211 us; speedup 1.0000x reference)
//
#include <hip/hip_runtime.h>
#include <hip/hip_bf16.h>

// Hard-batch-mining triplet loss, B=4096, D=2048, NCLS=64, margin=0.3.
// Pipeline: prep (fp32->bf16 + row norms + init) -> gram (bf16 MFMA GEMM with
// fused distance/mask/row-reduce epilogue) -> loss (mean relu).
// Workspace layout (needs 16 MiB + 48 KiB):
//   [0, 16MiB)      X in bf16, row-major 4096x2048
//   +0KB  sq[4096]  fp32 row squared norms
//   +16KB pos[4096] uint-ordered float, hardest-positive running max
//   +32KB neg[4096] uint-ordered float, hardest-negative running min

typedef __attribute__((ext_vector_type(8))) short short8;
typedef __attribute__((ext_vector_type(4))) float f32x4;
using bf16 = __hip_bfloat16;

#define BN_ROWS 4096
#define D_DIM   2048
#define TILE    128
#define BK      64
#define MARGIN  0.3f

__device__ __forceinline__ void gload16(const bf16* g, bf16* l) {
  __builtin_amdgcn_global_load_lds(
      (const __attribute__((address_space(1))) void*)g,
      (__attribute__((address_space(3))) void*)l, 16, 0, 0);
}

// ---------------- prep: convert + row norms + init reductions ----------------
__global__ __launch_bounds__(256) void prep_kernel(
    const float* __restrict__ x, bf16* __restrict__ xb, float* __restrict__ sqv,
    unsigned* __restrict__ pos, unsigned* __restrict__ neg) {
  const int row = blockIdx.x;
  const int t = threadIdx.x;
  const float4* xr = (const float4*)(x + (size_t)row * D_DIM) + (size_t)t * 2;
  float4 a = xr[0];
  float4 b = xr[1];
  float s = a.x * a.x + a.y * a.y + a.z * a.z + a.w * a.w +
            b.x * b.x + b.y * b.y + b.z * b.z + b.w * b.w;
  union { short8 v; bf16 h[8]; } u;
  u.h[0] = __float2bfloat16(a.x);
  u.h[1] = __float2bfloat16(a.y);
  u.h[2] = __float2bfloat16(a.z);
  u.h[3] = __float2bfloat16(a.w);
  u.h[4] = __float2bfloat16(b.x);
  u.h[5] = __float2bfloat16(b.y);
  u.h[6] = __float2bfloat16(b.z);
  u.h[7] = __float2bfloat16(b.w);
  *(short8*)(xb + (size_t)row * D_DIM + (size_t)t * 8) = u.v;

  #pragma unroll
  for (int o = 32; o; o >>= 1) s += __shfl_down(s, o, 64);
  __shared__ float red[4];
  if ((t & 63) == 0) red[t >> 6] = s;
  __syncthreads();
  if (t == 0) {
    sqv[row] = red[0] + red[1] + red[2] + red[3];
    pos[row] = 0u;           // distances >= 0; diagonal is always same-class
    neg[row] = 0x7F800000u;  // +inf
  }
}

// ---------------- gram: 128x128 bf16 MFMA tile + fused epilogue --------------
// 4 waves in 2x2, each computes 64x64 (4x4 fragments of 16x16x32).
// LDS tiles [128][64] bf16 with XOR swizzle: logical (row, c16) stored at
// byte (row*128 + ((c16 ^ (row&7))<<4)). global_load_lds writes linearly, so
// the *source* address is inverse-swizzled (rule: both-sides-or-neither).
__global__ __launch_bounds__(256) void gram_kernel(
    const bf16* __restrict__ xb, const float* __restrict__ sqv,
    const int* __restrict__ tgt, unsigned* __restrict__ pos,
    unsigned* __restrict__ neg) {
  __shared__ bf16 As[TILE * BK];
  __shared__ bf16 Bs[TILE * BK];
  const int t = threadIdx.x;
  const int wave = t >> 6, lane = t & 63;
  const int rowBase = blockIdx.y * TILE;
  const int colBase = blockIdx.x * TILE;
  const int wr = wave >> 1, wc = wave & 1;
  const int lhi = lane >> 4, llo = lane & 15;

  f32x4 acc[4][4];
  #pragma unroll
  for (int m = 0; m < 4; ++m)
    #pragma unroll
    for (int n = 0; n < 4; ++n) acc[m][n] = (f32x4){0.f, 0.f, 0.f, 0.f};

  // staging geometry: 16 chunks of 8 rows; wave w stages chunks [4w, 4w+4)
  const int srow = lane >> 3;                    // row within chunk, 0..7
  const int swz = (lane & 7) ^ srow;             // inverse-swizzled source c16

  for (int k0 = 0; k0 < D_DIM; k0 += BK) {
    #pragma unroll
    for (int c = 0; c < 4; ++c) {
      const int chunk = wave * 4 + c;
      const size_t kcol = (size_t)k0 + (size_t)swz * 8;
      gload16(xb + (size_t)(rowBase + chunk * 8 + srow) * D_DIM + kcol,
              As + chunk * 512);
      gload16(xb + (size_t)(colBase + chunk * 8 + srow) * D_DIM + kcol,
              Bs + chunk * 512);
    }
    asm volatile("s_waitcnt vmcnt(0)" ::: "memory");
    __syncthreads();

    #pragma unroll
    for (int kk = 0; kk < 2; ++kk) {
      short8 af[4], bfr[4];
      #pragma unroll
      for (int m = 0; m < 4; ++m) {
        const int row = wr * 64 + m * 16 + llo;
        const int c16 = (kk * 4 + lhi) ^ (row & 7);
        af[m] = *(const short8*)(As + row * 64 + c16 * 8);
      }
      #pragma unroll
      for (int n = 0; n < 4; ++n) {
        const int row = wc * 64 + n * 16 + llo;
        const int c16 = (kk * 4 + lhi) ^ (row & 7);
        bfr[n] = *(const short8*)(Bs + row * 64 + c16 * 8);
      }
      #pragma unroll
      for (int m = 0; m < 4; ++m)
        #pragma unroll
        for (int n = 0; n < 4; ++n)
          acc[m][n] = __builtin_amdgcn_mfma_f32_16x16x32_bf16(
              af[m], bfr[n], acc[m][n], 0, 0, 0);
    }
    __syncthreads();
  }

  // ---- fused epilogue: distance, class mask, per-row max/min, atomics ----
  float sqj[4];
  int tgj[4];
  #pragma unroll
  for (int n = 0; n < 4; ++n) {
    const int j = colBase + wc * 64 + n * 16 + llo;
    sqj[n] = sqv[j];
    tgj[n] = tgt[j];
  }
  #pragma unroll
  for (int m = 0; m < 4; ++m) {
    #pragma unroll
    for (int r = 0; r < 4; ++r) {
      const int i = rowBase + wr * 64 + m * 16 + lhi * 4 + r;
      const float sqi = sqv[i];
      const int tgi = tgt[i];
      float pm = 0.0f;
      float nm = __uint_as_float(0x7F800000u);
      #pragma unroll
      for (int n = 0; n < 4; ++n) {
        const float g = acc[m][n][r];
        const float d2 = sqi + sqj[n] - 2.0f * g;
        const float d = sqrtf(fmaxf(d2, 1e-12f));
        if (tgj[n] == tgi) pm = fmaxf(pm, d);
        else               nm = fminf(nm, d);
      }
      #pragma unroll
      for (int o = 1; o < 16; o <<= 1) {
        pm = fmaxf(pm, __shfl_xor(pm, o, 64));
        nm = fminf(nm, __shfl_xor(nm, o, 64));
      }
      if (llo == 0) {
        atomicMax(pos + i, __float_as_uint(pm));  // order-safe: d >= 0
        atomicMin(neg + i, __float_as_uint(nm));
      }
    }
  }
}

// ---------------- loss: mean(relu(d_pos - d_neg + margin)) -------------------
__global__ __launch_bounds__(1024) void loss_kernel(
    const unsigned* __restrict__ pos, const unsigned* __restrict__ neg,
    float* __restrict__ out) {
  const int t = threadIdx.x;
  float s = 0.f;
  for (int i = t; i < BN_ROWS; i += 1024) {
    const float dp = __uint_as_float(pos[i]);
    const float dn = __uint_as_float(neg[i]);
    const float v = dp - dn + MARGIN;
    s += v > 0.f ? v : 0.f;
  }
  #pragma unroll
  for (int o = 32; o; o >>= 1) s += __shfl_down(s, o, 64);
  __shared__ float red[16];
  if ((t & 63) == 0) red[t >> 6] = s;
  __syncthreads();
  if (t < 16) {
    float v = red[t];
    #pragma unroll
    for (int o = 8; o; o >>= 1) v += __shfl_down(v, o, 16);
    if (t == 0) out[0] = v * (1.0f / (float)BN_ROWS);
  }
}

extern "C" void kernel_launch(void* const* d_in, const int* in_sizes, int n_in,
                              void* d_out, int out_size, void* d_ws, size_t ws_size,
                              hipStream_t stream) {
  const float* x = (const float*)d_in[0];
  const int* tgt = (const int*)d_in[1];
  float* out = (float*)d_out;

  char* ws = (char*)d_ws;
  bf16* xb = (bf16*)ws;                                        // 16 MiB
  float* sqv = (float*)(ws + (size_t)BN_ROWS * D_DIM * 2);     // 16 KiB
  unsigned* pos = (unsigned*)((char*)sqv + BN_ROWS * 4);       // 16 KiB
  unsigned* neg = (unsigned*)((char*)pos + BN_ROWS * 4);       // 16 KiB

  prep_kernel<<<BN_ROWS, 256, 0, stream>>>(x, xb, sqv, pos, neg);
  gram_kernel<<<dim3(BN_ROWS / TILE, BN_ROWS / TILE), 256, 0, stream>>>(
      xb, sqv, tgt, pos, neg);
  loss_kernel<<<1, 1024, 0, stream>>>(pos, neg, out);
}